// Round 6
// baseline (445.913 us; speedup 1.0000x reference)
//
#include <hip/hip_runtime.h>
#include <hip/hip_bf16.h>

// SlotAttention: B=32, N=16384, D=64, S=7, H=128, 3 iterations.
//   wconv_kernel : Wk,Wv f32 -> bf16 once (8 KB, stays L2-hot for proj frag reads)
//   proj_kernel  : LN(inputs) -> k[b][n][d] + vT[b][d][n] bf16 via MFMA, 1 barrier,
//                  direct uint2 stores (R4 evidence: L2 merges, no write amplification)
//   init_kernel  : slots0, h0, zero acc, q0
//   3x { attn_kernel : A=q MFMA -> in-register softmax over s -> MFMA attn@vT, W/C atomics
//        slot_update : W/C -> GRU -> MLP -> slots -> next q }

#define B_ 32
#define N_ 16384
#define D_ 64
#define S_ 7

typedef __bf16 bf16x8 __attribute__((ext_vector_type(8)));
typedef float floatx4 __attribute__((ext_vector_type(4)));

__device__ __forceinline__ unsigned int f2bfu(float f) {
  __hip_bfloat16 h = __float2bfloat16(f);
  return (unsigned int)__builtin_bit_cast(unsigned short, h);
}
__device__ __forceinline__ unsigned int pack2bf(float lo, float hi) {
  return f2bfu(lo) | (f2bfu(hi) << 16);
}
__device__ __forceinline__ float sigmoid_f(float x) {
  return 1.f / (1.f + __expf(-x));
}
__device__ __forceinline__ float tanh_f(float x) {
  return 1.f - 2.f / (1.f + __expf(2.f * x));
}

// ---------------- weight convert: Wk|Wv f32 -> bf16 [128][64] ----------------
__global__ __launch_bounds__(256) void wconv_kernel(
    const float* __restrict__ Wk, const float* __restrict__ Wv,
    unsigned short* __restrict__ wbf)
{
  const int t = threadIdx.x;
#pragma unroll
  for (int p = 0; p < 4; ++p) {
    int idx = (p * 256 + t) * 8;
    const float* src = (idx < 4096) ? (Wk + idx) : (Wv + idx - 4096);
    float4 a = ((const float4*)src)[0], b = ((const float4*)src)[1];
    uint4 pk;
    pk.x = pack2bf(a.x, a.y); pk.y = pack2bf(a.z, a.w);
    pk.z = pack2bf(b.x, b.y); pk.w = pack2bf(b.z, b.w);
    *(uint4*)&wbf[idx] = pk;
  }
}

// ---------------- proj: LN + K/V projection ----------------
// k[b][n][d] bf16 (attn ph1 B-frags), vT[b][d][n] bf16 (attn ph2 B-frags).
__global__ __launch_bounds__(256) void proj_kernel(
    const float* __restrict__ x,
    const float* __restrict__ lng, const float* __restrict__ lnb,
    const unsigned short* __restrict__ wbf,
    unsigned short* __restrict__ kb, unsigned short* __restrict__ vt)
{
  __shared__ __align__(16) unsigned short s_xn[128 * 64];  // [row][d] xor-swizzled 16B chunks
  const int t = threadIdx.x, lane = t & 63, w = t >> 6;
  const int R0 = blockIdx.x * 128;
  const int bb = R0 >> 14;
  const int nbase = R0 & (N_ - 1);

  // prefetch x first (both halves), then LN params
  const int ql = t & 3;
  const int r0r = t >> 2;
  float4 xv0[4], xv1[4];
  {
    const float4* xp0 = (const float4*)&x[(size_t)(R0 + r0r) * 64 + ql * 16];
    const float4* xp1 = (const float4*)&x[(size_t)(R0 + 64 + r0r) * 64 + ql * 16];
#pragma unroll
    for (int j = 0; j < 4; ++j) xv0[j] = xp0[j];
#pragma unroll
    for (int j = 0; j < 4; ++j) xv1[j] = xp1[j];
  }
  float4 g4[4], b4[4];
#pragma unroll
  for (int j = 0; j < 4; ++j) {
    g4[j] = *(const float4*)&lng[ql * 16 + j * 4];
    b4[j] = *(const float4*)&lnb[ql * 16 + j * 4];
  }

#pragma unroll
  for (int half = 0; half < 2; ++half) {
    int r = half * 64 + r0r;
    float4* xv = half ? xv1 : xv0;
    float s1 = 0.f, s2 = 0.f;
#pragma unroll
    for (int j = 0; j < 4; ++j) {
      s1 += xv[j].x + xv[j].y + xv[j].z + xv[j].w;
      s2 += xv[j].x * xv[j].x + xv[j].y * xv[j].y + xv[j].z * xv[j].z + xv[j].w * xv[j].w;
    }
    s1 += __shfl_xor(s1, 1); s2 += __shfl_xor(s2, 1);
    s1 += __shfl_xor(s1, 2); s2 += __shfl_xor(s2, 2);
    float mean = s1 * 0.015625f;
    float var = s2 * 0.015625f - mean * mean;
    float rs = rsqrtf(var + 1e-5f);
    float y[16];
#pragma unroll
    for (int j = 0; j < 4; ++j) {
      y[j * 4 + 0] = (xv[j].x - mean) * rs * g4[j].x + b4[j].x;
      y[j * 4 + 1] = (xv[j].y - mean) * rs * g4[j].y + b4[j].y;
      y[j * 4 + 2] = (xv[j].z - mean) * rs * g4[j].z + b4[j].z;
      y[j * 4 + 3] = (xv[j].w - mean) * rs * g4[j].w + b4[j].w;
    }
#pragma unroll
    for (int h = 0; h < 2; ++h) {
      uint4 p;
      p.x = pack2bf(y[h * 8 + 0], y[h * 8 + 1]);
      p.y = pack2bf(y[h * 8 + 2], y[h * 8 + 3]);
      p.z = pack2bf(y[h * 8 + 4], y[h * 8 + 5]);
      p.w = pack2bf(y[h * 8 + 6], y[h * 8 + 7]);
      int c = ql * 2 + h;
      int sc = c ^ (r & 7);
      *(uint4*)&s_xn[r * 64 + sc * 8] = p;
    }
  }
  __syncthreads();

  const int m16 = lane & 15, quad = lane >> 4;
  bf16x8 bf[2][2];
#pragma unroll
  for (int rt = 0; rt < 2; ++rt) {
    int xr = (w * 2 + rt) * 16 + m16;
#pragma unroll
    for (int kk = 0; kk < 2; ++kk)
      bf[rt][kk] = *(const bf16x8*)&s_xn[xr * 64 + (((kk * 4 + quad) ^ (xr & 7)) * 8)];
  }

  // k-part: A=Wk (m=d), B=xn (n'=n). lane: 4 consecutive d for n=m16 -> uint2 store
#pragma unroll
  for (int ft = 0; ft < 4; ++ft) {
    bf16x8 wk0 = *(const bf16x8*)&wbf[(ft * 16 + m16) * 64 + quad * 8];
    bf16x8 wk1 = *(const bf16x8*)&wbf[(ft * 16 + m16) * 64 + 32 + quad * 8];
#pragma unroll
    for (int rt = 0; rt < 2; ++rt) {
      floatx4 acc = (floatx4){0.f, 0.f, 0.f, 0.f};
      acc = __builtin_amdgcn_mfma_f32_16x16x32_bf16(wk0, bf[rt][0], acc, 0, 0, 0);
      acc = __builtin_amdgcn_mfma_f32_16x16x32_bf16(wk1, bf[rt][1], acc, 0, 0, 0);
      int n_l = (w * 2 + rt) * 16 + m16;
      int d0 = ft * 16 + quad * 4;
      uint2 p;
      p.x = pack2bf(acc[0], acc[1]);
      p.y = pack2bf(acc[2], acc[3]);
      *(uint2*)&kb[(size_t)(R0 + n_l) * 64 + d0] = p;
    }
  }

  // v-part: A=xn (m=n), B=Wv (n'=d). lane: 4 consecutive n for d=ft*16+m16 -> uint2 store
#pragma unroll
  for (int ft = 0; ft < 4; ++ft) {
    bf16x8 wv0 = *(const bf16x8*)&wbf[(64 + ft * 16 + m16) * 64 + quad * 8];
    bf16x8 wv1 = *(const bf16x8*)&wbf[(64 + ft * 16 + m16) * 64 + 32 + quad * 8];
#pragma unroll
    for (int rt = 0; rt < 2; ++rt) {
      floatx4 acc = (floatx4){0.f, 0.f, 0.f, 0.f};
      acc = __builtin_amdgcn_mfma_f32_16x16x32_bf16(bf[rt][0], wv0, acc, 0, 0, 0);
      acc = __builtin_amdgcn_mfma_f32_16x16x32_bf16(bf[rt][1], wv1, acc, 0, 0, 0);
      int n_l = nbase + (w * 2 + rt) * 16 + quad * 4;
      int d0 = ft * 16 + m16;
      uint2 p;
      p.x = pack2bf(acc[0], acc[1]);
      p.y = pack2bf(acc[2], acc[3]);
      *(uint2*)&vt[((size_t)bb * 64 + d0) * N_ + n_l] = p;
    }
  }
}

// ---------------- shared helper: q = LN(slots; ln_slots) @ Wq^T * scale ----------------
__device__ void q_from_slots(const float* s_slot, float* s_tmp,
                             const float* __restrict__ g, const float* __restrict__ bb,
                             const float* __restrict__ Wq, float* __restrict__ qout,
                             int lane, int w)
{
  for (int ss = 0; ss < 2; ++ss) {
    int srow = ss * 4 + w;
    if (srow < 7) {
      float xv = s_slot[srow * 64 + lane];
      float s1 = xv, s2 = xv * xv;
#pragma unroll
      for (int mm = 1; mm < 64; mm <<= 1) {
        s1 += __shfl_xor(s1, mm);
        s2 += __shfl_xor(s2, mm);
      }
      float mean = s1 * 0.015625f;
      float var = s2 * 0.015625f - mean * mean;
      float rs = rsqrtf(var + 1e-5f);
      s_tmp[w * 64 + lane] = (xv - mean) * rs * g[lane] + bb[lane];
    }
    __syncthreads();
    if (srow < 7) {
      float acc = 0.f;
      const float4* wr = (const float4*)(Wq + lane * 64);
      const float4* xr = (const float4*)(s_tmp + w * 64);
#pragma unroll
      for (int i = 0; i < 16; ++i) {
        float4 a = wr[i], xx = xr[i];
        acc += a.x * xx.x + a.y * xx.y + a.z * xx.z + a.w * xx.w;
      }
      qout[srow * 64 + lane] = acc * 0.125f;
    }
    __syncthreads();
  }
}

// ---------------- init ----------------
__global__ __launch_bounds__(256) void init_kernel(
    const float* __restrict__ mu, const float* __restrict__ lsig,
    const float* __restrict__ nslots, const float* __restrict__ nh,
    const float* __restrict__ ln_s_g, const float* __restrict__ ln_s_b,
    const float* __restrict__ Wq,
    float* __restrict__ qbuf, float* __restrict__ Wacc, float* __restrict__ Cacc,
    float* __restrict__ h0b)
{
  __shared__ float s_slot[448];
  __shared__ float s_tmp[256];
  const int b = blockIdx.x, t = threadIdx.x, lane = t & 63, w = t >> 6;
  for (int o = t; o < 448; o += 256) {
    int d = o & 63;
    s_slot[o] = mu[d] + expf(lsig[d]) * nslots[b * 448 + o];
    Wacc[b * 448 + o] = 0.f;
  }
  if (t < 64) h0b[b * 64 + t] = mu[t] + expf(lsig[t]) * nh[b * 64 + t];
  if (t < 8) Cacc[b * 8 + t] = 0.f;
  __syncthreads();
  q_from_slots(s_slot, s_tmp, ln_s_g, ln_s_b, Wq, qbuf + b * 448, lane, w);
}

// ---------------- attention pass (MFMA, in-register softmax) ----------------
// grid (64,32): block = 256 n of one b; wave = 64 n (4 tiles of 16).
// ph1: D = mfma(A=q, B=k) -> logits[s=quad*4+rg][n=m16] in-register; softmax over s
//      = 3 in-reg max + 1 xor16 shuffle + exps + 1 xor16 shuffle. Store bf16 attn to s_at[s][n].
// ph2: D = mfma(A=attn, B=vT) -> upd[s][d] accumulated over 2 n-chunks of 32.
__global__ __launch_bounds__(256) void attn_kernel(
    const unsigned short* __restrict__ kb, const unsigned short* __restrict__ vt,
    const float* __restrict__ qbuf,
    float* __restrict__ Wacc, float* __restrict__ Cacc)
{
  __shared__ __align__(16) unsigned short s_qb[16 * 64];     // q bf16 [s][d], rows 7..15 = 0
  __shared__ __align__(16) unsigned short s_at[4][16 * 72];  // per-wave attn bf16 [s][n(64)+pad]
  __shared__ __align__(16) float s_red[4][448];
  __shared__ float s_cred[4][8];

  const int b = blockIdx.y;
  const int t = threadIdx.x, lane = t & 63, w = t >> 6;
  const int m16 = lane & 15, quad = lane >> 4;

  {
    int i0 = t * 4;
    int s = i0 >> 6, d0 = i0 & 63;
    float f0 = 0.f, f1 = 0.f, f2 = 0.f, f3 = 0.f;
    if (s < 7) {
      const float* qp = qbuf + b * 448 + s * 64 + d0;
      f0 = qp[0]; f1 = qp[1]; f2 = qp[2]; f3 = qp[3];
    }
    uint2 p;
    p.x = pack2bf(f0, f1);
    p.y = pack2bf(f2, f3);
    *(uint2*)&s_qb[i0] = p;
  }
  __syncthreads();

  bf16x8 aq0 = *(const bf16x8*)&s_qb[m16 * 64 + quad * 8];
  bf16x8 aq1 = *(const bf16x8*)&s_qb[m16 * 64 + 32 + quad * 8];

  const int n0g = blockIdx.x * 256 + w * 64;  // within b
  const unsigned short* kbA = kb + ((size_t)b * N_ + n0g) * 64;

  float clp[4] = {0.f, 0.f, 0.f, 0.f};  // per-lane attn col-sum for s=quad*4+rg (quad<2)

#pragma unroll
  for (int nt = 0; nt < 4; ++nt) {
    bf16x8 bk0 = *(const bf16x8*)&kbA[(size_t)(nt * 16 + m16) * 64 + quad * 8];
    bf16x8 bk1 = *(const bf16x8*)&kbA[(size_t)(nt * 16 + m16) * 64 + 32 + quad * 8];
    floatx4 c = (floatx4){0.f, 0.f, 0.f, 0.f};
    c = __builtin_amdgcn_mfma_f32_16x16x32_bf16(aq0, bk0, c, 0, 0, 0);
    c = __builtin_amdgcn_mfma_f32_16x16x32_bf16(aq1, bk1, c, 0, 0, 0);
    // lane holds logits[s = quad*4+rg][n = nt*16+m16]; quads 0,1 valid (s<8), s=7 masked
    float v0 = c[0], v1 = c[1], v2 = c[2], v3 = c[3];
    if (quad == 1) v3 = -1e30f;  // s = 7 invalid
    float mx = fmaxf(fmaxf(v0, v1), fmaxf(v2, v3));
    float M = fmaxf(mx, __shfl_xor(mx, 16));  // quad0<->quad1 (quad2/3 pair separately, junk)
    float e0 = __expf(v0 - M), e1 = __expf(v1 - M), e2 = __expf(v2 - M), e3 = __expf(v3 - M);
    float s4 = e0 + e1 + e2 + e3;
    float tot = s4 + __shfl_xor(s4, 16);
    float inv = 1.f / tot;
    float a0 = e0 * inv + 1e-8f, a1 = e1 * inv + 1e-8f;
    float a2 = e2 * inv + 1e-8f, a3 = e3 * inv + 1e-8f;
    if (quad < 2) {
      clp[0] += a0; clp[1] += a1; clp[2] += a2; clp[3] += a3;
      s_at[w][(quad * 4 + 0) * 72 + nt * 16 + m16] = (unsigned short)f2bfu(a0);
      s_at[w][(quad * 4 + 1) * 72 + nt * 16 + m16] = (unsigned short)f2bfu(a1);
      s_at[w][(quad * 4 + 2) * 72 + nt * 16 + m16] = (unsigned short)f2bfu(a2);
      if (quad == 0) s_at[w][3 * 72 + nt * 16 + m16] = (unsigned short)f2bfu(a3);
    }
  }
  // wave-private LDS write->read ordering (cross-lane through LDS)
  asm volatile("s_waitcnt lgkmcnt(0)" ::: "memory");

  // ph2: upd[s][d] = sum_n attn[s][n] * v[n][d]
  floatx4 acc[4];
#pragma unroll
  for (int dt = 0; dt < 4; ++dt) acc[dt] = (floatx4){0.f, 0.f, 0.f, 0.f};
  const unsigned short* vtB = vt + (size_t)b * 64 * N_ + n0g;
#pragma unroll
  for (int ch = 0; ch < 2; ++ch) {
    bf16x8 af = *(const bf16x8*)&s_at[w][m16 * 72 + ch * 32 + quad * 8];
#pragma unroll
    for (int dt = 0; dt < 4; ++dt) {
      bf16x8 bv = *(const bf16x8*)&vtB[(size_t)(dt * 16 + m16) * N_ + ch * 32 + quad * 8];
      acc[dt] = __builtin_amdgcn_mfma_f32_16x16x32_bf16(af, bv, acc[dt], 0, 0, 0);
    }
  }
  // D: lane holds upd[s=quad*4+rg][d=dt*16+m16]; valid s<7 (quad<2)
  if (quad < 2) {
#pragma unroll
    for (int dt = 0; dt < 4; ++dt)
#pragma unroll
      for (int rg = 0; rg < 4; ++rg) {
        int s = quad * 4 + rg;
        if (s < 7) s_red[w][s * 64 + dt * 16 + m16] = acc[dt][rg];
      }
  }
  // cl: reduce clp over the 16 m16 lanes
#pragma unroll
  for (int rg = 0; rg < 4; ++rg) {
    float c = clp[rg];
    c += __shfl_xor(c, 1);
    c += __shfl_xor(c, 2);
    c += __shfl_xor(c, 4);
    c += __shfl_xor(c, 8);
    clp[rg] = c;
  }
  if (m16 == 0 && quad < 2) {
#pragma unroll
    for (int rg = 0; rg < 4; ++rg) {
      int s = quad * 4 + rg;
      if (s < 7) s_cred[w][s] = clp[rg];
    }
  }
  __syncthreads();
  if (w == 0) {
#pragma unroll
    for (int s = 0; s < 7; ++s) {
      float v = s_red[0][s * 64 + lane] + s_red[1][s * 64 + lane] +
                s_red[2][s * 64 + lane] + s_red[3][s * 64 + lane];
      atomicAdd(&Wacc[b * 448 + s * 64 + lane], v);
    }
    if (lane < 7) {
      float c = s_cred[0][lane] + s_cred[1][lane] + s_cred[2][lane] + s_cred[3][lane];
      atomicAdd(&Cacc[b * 8 + lane], c);
    }
  }
}

// ---------------- slot update ----------------
__global__ __launch_bounds__(256) void slot_update_kernel(
    float* __restrict__ Wacc, float* __restrict__ Cacc,
    const float* __restrict__ h0b,
    const float* __restrict__ w_ih, const float* __restrict__ w_hh,
    const float* __restrict__ b_ih, const float* __restrict__ b_hh,
    const float* __restrict__ ln_m_g, const float* __restrict__ ln_m_b,
    const float* __restrict__ w1, const float* __restrict__ b1,
    const float* __restrict__ w2, const float* __restrict__ b2,
    const float* __restrict__ ln_s_g, const float* __restrict__ ln_s_b,
    const float* __restrict__ Wq,
    float* __restrict__ qbuf, float* __restrict__ out)
{
  const int b = blockIdx.x, t = threadIdx.x, lane = t & 63, w = t >> 6;
  __shared__ float s_whhT[64 * 201];
  __shared__ float s_upd[448];
  __shared__ float s_gi[1344];
  __shared__ float s_h[64];
  __shared__ float s_gh[192];
  __shared__ float s_slot[448];
  __shared__ float s_tmp[256];

  for (int i = t; i < 12288; i += 256) {
    int j = i >> 6, d = i & 63;
    s_whhT[d * 201 + j] = w_hh[i];
  }
  for (int o = t; o < 448; o += 256) {
    int s = o >> 6;
    s_upd[o] = Wacc[b * 448 + o] / Cacc[b * 8 + s];
  }
  if (t < 64) s_h[t] = h0b[b * 64 + t];
  __syncthreads();
  for (int o = t; o < 1344; o += 256) {
    int s = o / 192, j = o - s * 192;
    float acc = b_ih[j];
    const float4* wr = (const float4*)(w_ih + j * 64);
    const float4* ur = (const float4*)(s_upd + s * 64);
#pragma unroll
    for (int i = 0; i < 16; ++i) {
      float4 a = wr[i], u = ur[i];
      acc += a.x * u.x + a.y * u.y + a.z * u.z + a.w * u.w;
    }
    s_gi[o] = acc;
  }
  __syncthreads();
  for (int s = 0; s < 7; ++s) {
    if (t < 192) {
      float acc = b_hh[t];
#pragma unroll 16
      for (int d = 0; d < 64; ++d) acc += s_h[d] * s_whhT[d * 201 + t];
      s_gh[t] = acc;
    }
    __syncthreads();
    if (t < 64) {
      float ir = s_gi[s * 192 + t], iz = s_gi[s * 192 + 64 + t], inn = s_gi[s * 192 + 128 + t];
      float hr = s_gh[t], hz = s_gh[64 + t], hn = s_gh[128 + t];
      float r = sigmoid_f(ir + hr);
      float z = sigmoid_f(iz + hz);
      float n = tanh_f(inn + r * hn);
      float hnew = (1.f - z) * n + z * s_h[t];
      s_slot[s * 64 + t] = hnew;
      s_h[t] = hnew;
    }
    __syncthreads();
  }
  float* s_sn = s_gi;
  float* s_hid = s_gi + 448;
  for (int ss = 0; ss < 2; ++ss) {
    int srow = ss * 4 + w;
    if (srow < 7) {
      float xv = s_slot[srow * 64 + lane];
      float s1 = xv, s2 = xv * xv;
#pragma unroll
      for (int mm = 1; mm < 64; mm <<= 1) {
        s1 += __shfl_xor(s1, mm);
        s2 += __shfl_xor(s2, mm);
      }
      float mean = s1 * 0.015625f;
      float var = s2 * 0.015625f - mean * mean;
      float rs = rsqrtf(var + 1e-5f);
      s_sn[srow * 64 + lane] = (xv - mean) * rs * ln_m_g[lane] + ln_m_b[lane];
    }
  }
  __syncthreads();
  for (int o = t; o < 896; o += 256) {
    int s = o >> 7, hh = o & 127;
    float acc = b1[hh];
    const float4* wr = (const float4*)(w1 + hh * 64);
    const float4* xr = (const float4*)(s_sn + s * 64);
#pragma unroll
    for (int i = 0; i < 16; ++i) {
      float4 a = wr[i], xx = xr[i];
      acc += a.x * xx.x + a.y * xx.y + a.z * xx.z + a.w * xx.w;
    }
    s_hid[o] = fmaxf(acc, 0.f);
  }
  __syncthreads();
  for (int o = t; o < 448; o += 256) {
    int s = o >> 6, d = o & 63;
    float acc = b2[d];
    const float4* wr = (const float4*)(w2 + d * 128);
    const float4* hr = (const float4*)(s_hid + s * 128);
#pragma unroll
    for (int i = 0; i < 32; ++i) {
      float4 a = wr[i], hv = hr[i];
      acc += a.x * hv.x + a.y * hv.y + a.z * hv.z + a.w * hv.w;
    }
    float val = s_slot[o] + acc;
    s_slot[o] = val;
    out[b * 448 + o] = val;
  }
  for (int o = t; o < 448; o += 256) Wacc[b * 448 + o] = 0.f;
  if (t < 8) Cacc[b * 8 + t] = 0.f;
  __syncthreads();
  q_from_slots(s_slot, s_tmp, ln_s_g, ln_s_b, Wq, qbuf + b * 448, lane, w);
}

extern "C" void kernel_launch(void* const* d_in, const int* in_sizes, int n_in,
                              void* d_out, int out_size, void* d_ws, size_t ws_size,
                              hipStream_t stream)
{
  (void)in_sizes; (void)n_in; (void)out_size; (void)ws_size;
  const float* x      = (const float*)d_in[0];
  const float* ln_in_g = (const float*)d_in[1];
  const float* ln_in_b = (const float*)d_in[2];
  const float* ln_s_g  = (const float*)d_in[3];
  const float* ln_s_b  = (const float*)d_in[4];
  const float* ln_m_g  = (const float*)d_in[5];
  const float* ln_m_b  = (const float*)d_in[6];
  const float* Wq = (const float*)d_in[7];
  const float* Wk = (const float*)d_in[8];
  const float* Wv = (const float*)d_in[9];
  const float* mu = (const float*)d_in[10];
  const float* lsig = (const float*)d_in[11];
  const float* w_ih = (const float*)d_in[12];
  const float* w_hh = (const float*)d_in[13];
  const float* b_ih = (const float*)d_in[14];
  const float* b_hh = (const float*)d_in[15];
  const float* w1 = (const float*)d_in[16];
  const float* b1 = (const float*)d_in[17];
  const float* w2 = (const float*)d_in[18];
  const float* b2 = (const float*)d_in[19];
  const float* nslots = (const float*)d_in[20];
  const float* nh = (const float*)d_in[21];

  unsigned short* kb = (unsigned short*)d_ws;                 // k[b][n][d] bf16
  unsigned short* vt = kb + (size_t)B_ * N_ * D_;             // vT[b][d][n] bf16
  float* fb = (float*)(vt + (size_t)B_ * N_ * D_);
  float* qbuf = fb;            // 32*448
  float* Wacc = fb + 14336;    // 32*448
  float* Cacc = fb + 28672;    // 32*8
  float* h0b  = fb + 28928;    // 32*64
  unsigned short* wbf = (unsigned short*)(fb + 30976);  // 128*64 bf16 weights
  float* out = (float*)d_out;

  wconv_kernel<<<1, 256, 0, stream>>>(Wk, Wv, wbf);
  proj_kernel<<<4096, 256, 0, stream>>>(x, ln_in_g, ln_in_b, wbf, kb, vt);
  init_kernel<<<32, 256, 0, stream>>>(mu, lsig, nslots, nh, ln_s_g, ln_s_b, Wq,
                                      qbuf, Wacc, Cacc, h0b);
  for (int it = 0; it < 3; ++it) {
    attn_kernel<<<dim3(64, 32), 256, 0, stream>>>(kb, vt, qbuf, Wacc, Cacc);
    slot_update_kernel<<<32, 256, 0, stream>>>(Wacc, Cacc, h0b, w_ih, w_hh, b_ih, b_hh,
                                               ln_m_g, ln_m_b, w1, b1, w2, b2,
                                               ln_s_g, ln_s_b, Wq, qbuf, out);
  }
}